// Round 1
// baseline (291.968 us; speedup 1.0000x reference)
//
#include <hip/hip_runtime.h>
#include <hip/hip_bf16.h>

// Problem constants
#define B_SZ   4
#define DEC_SZ 128
#define ENC_SZ 512
#define H_SZ   768

// ---------------------------------------------------------------------------
// Tiled fp32 GEMM: C = A @ W   (A: (B, M, H), W: (H, H) row-major (h, n))
// TOUT=false: C[b][m][n]  (row len H)
// TOUT=true : C[b][n][m]  (row len M)  -- transposed output for the score kernel
// Block: 256 threads, 64x64 tile, 4x4 microtile, BK=16.
// ---------------------------------------------------------------------------
template <bool TOUT>
__global__ __launch_bounds__(256) void gemm_tile(const float* __restrict__ A,
                                                 const float* __restrict__ W,
                                                 float* __restrict__ C, int M) {
  const int b  = blockIdx.z;
  const int m0 = blockIdx.x * 64;
  const int n0 = blockIdx.y * 64;
  const float* Ab = A + (size_t)b * M * H_SZ;

  const int tid = threadIdx.x;
  const int tx = tid & 15;   // m-group
  const int ty = tid >> 4;   // n-group

  __shared__ float As[16][65];  // [h][m], padded to kill 16-way write conflict
  __shared__ float Ws[16][64];  // [h][n]

  float acc[4][4] = {};

  for (int h0 = 0; h0 < H_SZ; h0 += 16) {
#pragma unroll
    for (int i = 0; i < 4; ++i) {
      int idx = tid + 256 * i;          // 0..1023 over 64m x 16h (h fastest)
      int m = idx >> 4, h = idx & 15;
      As[h][m] = Ab[(size_t)(m0 + m) * H_SZ + h0 + h];
    }
#pragma unroll
    for (int i = 0; i < 4; ++i) {
      int idx = tid + 256 * i;          // 0..1023 over 16h x 64n (n fastest)
      int h = idx >> 6, n = idx & 63;
      Ws[h][n] = W[(size_t)(h0 + h) * H_SZ + n0 + n];
    }
    __syncthreads();
#pragma unroll
    for (int hh = 0; hh < 16; ++hh) {
      float a[4], w[4];
#pragma unroll
      for (int i = 0; i < 4; ++i) a[i] = As[hh][tx + 16 * i];
#pragma unroll
      for (int j = 0; j < 4; ++j) w[j] = Ws[hh][ty + 16 * j];
#pragma unroll
      for (int i = 0; i < 4; ++i)
#pragma unroll
        for (int j = 0; j < 4; ++j) acc[i][j] = fmaf(a[i], w[j], acc[i][j]);
    }
    __syncthreads();
  }

  if (TOUT) {
    float* Cb = C + (size_t)b * H_SZ * M;  // [n][m], row len M
#pragma unroll
    for (int j = 0; j < 4; ++j) {
      int n = n0 + ty + 16 * j;
#pragma unroll
      for (int i = 0; i < 4; ++i) {
        int m = m0 + tx + 16 * i;
        Cb[(size_t)n * M + m] = acc[i][j];
      }
    }
  } else {
    float* Cb = C + (size_t)b * M * H_SZ;  // [m][n], row len H
#pragma unroll
    for (int i = 0; i < 4; ++i) {
      int m = m0 + tx + 16 * i;
#pragma unroll
      for (int j = 0; j < 4; ++j) {
        int n = n0 + ty + 16 * j;
        Cb[(size_t)m * H_SZ + n] = acc[i][j];
      }
    }
  }
}

// ---------------------------------------------------------------------------
// Score kernel: part[kc][b][d][e] = sum_{k in chunk} vt[k] * (implicit tanh)
// We accumulate t = sum vk * rcp(1 + e^{2x}) and emit sumv - 2*t, since
// tanh(x) = 1 - 2/(1+e^{2x}).
// Grid: (ENC/256, DEC/8, B*4). Block: 256 threads, lane = e.
// encT layout (B, H, ENC) gives coalesced loads; dec/vt broadcast from LDS.
// ---------------------------------------------------------------------------
#define D_CHUNK 8
#define K_CHUNK 192
#define NKC     4

__global__ __launch_bounds__(256) void score_kernel(const float* __restrict__ encT,
                                                    const float* __restrict__ dect,
                                                    const float* __restrict__ vt,
                                                    float* __restrict__ part) {
  const int e  = blockIdx.x * 256 + threadIdx.x;
  const int d0 = blockIdx.y * D_CHUNK;
  const int bz = blockIdx.z;
  const int b  = bz >> 2;
  const int kc = bz & 3;
  const int k0 = kc * K_CHUNK;
  const int tid = threadIdx.x;

  __shared__ float dec_s[K_CHUNK][D_CHUNK];  // [k][d] for broadcast b128 reads
  __shared__ float vts[K_CHUNK];

#pragma unroll
  for (int i = 0; i < 6; ++i) {
    int idx = tid + 256 * i;              // 0..1535 over 8d x 192k (k fastest)
    int d = idx / K_CHUNK, k = idx % K_CHUNK;
    dec_s[k][d] = dect[((size_t)b * DEC_SZ + d0 + d) * H_SZ + k0 + k];
  }
  if (tid < K_CHUNK) vts[tid] = vt[k0 + tid];
  __syncthreads();

  float sumv = 0.f;
  for (int k = 0; k < K_CHUNK; ++k) sumv += vts[k];

  float t[D_CHUNK];
#pragma unroll
  for (int d = 0; d < D_CHUNK; ++d) t[d] = 0.f;

  const float* ep = encT + ((size_t)b * H_SZ + k0) * ENC_SZ + e;
  const float C2 = 2.885390082f;  // 2 * log2(e)

#pragma unroll 2
  for (int k = 0; k < K_CHUNK; ++k) {
    float encv = ep[(size_t)k * ENC_SZ];
    float vk = vts[k];
    const float4 da = *(const float4*)&dec_s[k][0];
    const float4 db = *(const float4*)&dec_s[k][4];
    float dv[8] = {da.x, da.y, da.z, da.w, db.x, db.y, db.z, db.w};
#pragma unroll
    for (int d = 0; d < D_CHUNK; ++d) {
      float x = (encv + dv[d]) * C2;
      float p = exp2f(x);                       // e^{2x} via v_exp_f32
      float r = __builtin_amdgcn_rcpf(p + 1.f); // 1/(1+e^{2x})
      t[d] = fmaf(vk, r, t[d]);
    }
  }

  float* pp = part + (size_t)kc * (B_SZ * DEC_SZ * ENC_SZ) +
              ((size_t)b * DEC_SZ + d0) * ENC_SZ + e;
#pragma unroll
  for (int d = 0; d < D_CHUNK; ++d)
    pp[(size_t)d * ENC_SZ] = fmaf(-2.f, t[d], sumv);
}

// ---------------------------------------------------------------------------
// Finalize: sum 4 k-partials, add mask, write both outputs (float4 vectorized)
// ---------------------------------------------------------------------------
__global__ __launch_bounds__(256) void finalize_kernel(const float* __restrict__ part,
                                                       const float* __restrict__ mask,
                                                       float* __restrict__ out) {
  const int N  = B_SZ * DEC_SZ * ENC_SZ;   // 262144
  const int N4 = N / 4;                    // 65536
  int i = blockIdx.x * 256 + threadIdx.x;
  if (i >= N4) return;
  const float4* p = (const float4*)part;
  float4 a = p[i];
  float4 b = p[i + N4];
  float4 c = p[i + 2 * N4];
  float4 d = p[i + 3 * N4];
  float4 s;
  s.x = a.x + b.x + c.x + d.x;
  s.y = a.y + b.y + c.y + d.y;
  s.z = a.z + b.z + c.z + d.z;
  s.w = a.w + b.w + c.w + d.w;
  float4 m = ((const float4*)mask)[i];
  float4 sm;
  sm.x = s.x + m.x; sm.y = s.y + m.y; sm.z = s.z + m.z; sm.w = s.w + m.w;
  ((float4*)out)[i] = sm;           // log_score_masked
  ((float4*)(out + N))[i] = s;      // log_score
}

extern "C" void kernel_launch(void* const* d_in, const int* in_sizes, int n_in,
                              void* d_out, int out_size, void* d_ws, size_t ws_size,
                              hipStream_t stream) {
  (void)in_sizes; (void)n_in; (void)out_size; (void)ws_size;
  const float* dec  = (const float*)d_in[0];  // (B, DEC, H)
  const float* enc  = (const float*)d_in[1];  // (B, ENC, H)
  const float* mask = (const float*)d_in[2];  // (B, DEC, ENC)
  const float* W1   = (const float*)d_in[3];  // (H, H)
  const float* W2   = (const float*)d_in[4];  // (H, H)
  const float* vt   = (const float*)d_in[5];  // (H,)
  float* out = (float*)d_out;

  // Workspace layout
  float* encT  = (float*)d_ws;                                   // B*H*ENC
  float* dect  = encT + (size_t)B_SZ * H_SZ * ENC_SZ;            // B*DEC*H
  float* part  = dect + (size_t)B_SZ * DEC_SZ * H_SZ;            // 4*B*DEC*ENC

  // enc_t transposed: (B, H, ENC)
  gemm_tile<true><<<dim3(ENC_SZ / 64, H_SZ / 64, B_SZ), 256, 0, stream>>>(
      enc, W1, encT, ENC_SZ);
  // dec_t normal: (B, DEC, H)
  gemm_tile<false><<<dim3(DEC_SZ / 64, H_SZ / 64, B_SZ), 256, 0, stream>>>(
      dec, W2, dect, DEC_SZ);
  // score partials over 4 k-chunks
  score_kernel<<<dim3(ENC_SZ / 256, DEC_SZ / D_CHUNK, B_SZ * NKC), 256, 0, stream>>>(
      encT, dect, vt, part);
  // reduce + mask + write both outputs
  finalize_kernel<<<dim3((B_SZ * DEC_SZ * ENC_SZ / 4 + 255) / 256), 256, 0, stream>>>(
      part, mask, out);
}

// Round 2
// 145.703 us; speedup vs baseline: 2.0039x; 2.0039x over previous
//
#include <hip/hip_runtime.h>
#include <hip/hip_bf16.h>

#define B_SZ   4
#define DEC_SZ 128
#define ENC_SZ 512
#define H_SZ   768

typedef __attribute__((ext_vector_type(8))) short s8v;   // 8 bf16 (4 VGPRs)
typedef __attribute__((ext_vector_type(4))) float fvec4; // MFMA accumulator

// fp32 -> bf16, round-to-nearest-even
__device__ inline unsigned short f2bf(float x) {
  union { float f; unsigned u; } v; v.f = x;
  unsigned r = v.u + 0x7FFF + ((v.u >> 16) & 1);
  return (unsigned short)(r >> 16);
}

// ---------------------------------------------------------------------------
// Prep: transpose W (768x768 fp32, (k,n)) -> WT bf16 (n,k). z selects W1/W2.
// ---------------------------------------------------------------------------
__global__ __launch_bounds__(256) void transpose_w(const float* __restrict__ W1,
                                                   const float* __restrict__ W2,
                                                   unsigned short* __restrict__ T1,
                                                   unsigned short* __restrict__ T2) {
  const float* W = blockIdx.z ? W2 : W1;
  unsigned short* T = blockIdx.z ? T2 : T1;
  __shared__ float tile[64][65];
  int c0 = blockIdx.x * 64;
  int r0 = blockIdx.y * 64;
  int tx = threadIdx.x & 63, ty = threadIdx.x >> 6;
#pragma unroll
  for (int i = 0; i < 16; ++i) {
    int r = ty + i * 4;
    tile[r][tx] = W[(size_t)(r0 + r) * H_SZ + c0 + tx];
  }
  __syncthreads();
#pragma unroll
  for (int i = 0; i < 16; ++i) {
    int c = ty + i * 4;
    T[(size_t)(c0 + c) * H_SZ + r0 + tx] = f2bf(tile[tx][c]);
  }
}

// Prep: fp32 -> bf16 elementwise (n4 = element count / 4)
__global__ __launch_bounds__(256) void cast_bf16(const float* __restrict__ x,
                                                 unsigned short* __restrict__ y, int n4) {
  int i = blockIdx.x * 256 + threadIdx.x;
  if (i >= n4) return;
  float4 v = ((const float4*)x)[i];
  ushort4 o;
  o.x = f2bf(v.x); o.y = f2bf(v.y); o.z = f2bf(v.z); o.w = f2bf(v.w);
  ((ushort4*)y)[i] = o;
}

// ---------------------------------------------------------------------------
// MFMA NT GEMM with exp2 epilogue: C[b][m][n] = exp2(C2 * sum_k A[m][k]*B[n][k])
// A, B bf16 row-major with row length H (k-contiguous). Tile 128x128, BK=32,
// 4 waves each computing 64x64 via 4x4 grid of 16x16x32 MFMAs.
// ---------------------------------------------------------------------------
__global__ __launch_bounds__(256) void gemm_nt_exp(const unsigned short* __restrict__ A,
                                                   size_t strideA,
                                                   const unsigned short* __restrict__ Bm,
                                                   size_t strideB,
                                                   float* __restrict__ C, size_t strideC,
                                                   int ldc) {
  const int b  = blockIdx.z;
  const int m0 = blockIdx.x * 128;
  const int n0 = blockIdx.y * 128;
  const unsigned short* Ab = A + strideA * (size_t)b;
  const unsigned short* Bb = Bm + strideB * (size_t)b;

  // pad to 40 bf16 (80 B = 20 words): rows 0..7 tile all 32 banks exactly
  __shared__ unsigned short As[128][40];
  __shared__ unsigned short Bs[128][40];

  const int tid  = threadIdx.x;
  const int wave = tid >> 6;
  const int lane = tid & 63;
  const int l16  = lane & 15;
  const int quad = lane >> 4;
  const int wm = (wave & 1) * 64;
  const int wn = (wave >> 1) * 64;

  fvec4 acc[4][4];
#pragma unroll
  for (int i = 0; i < 4; ++i)
#pragma unroll
    for (int j = 0; j < 4; ++j) acc[i][j] = (fvec4)0.f;

  for (int k0 = 0; k0 < H_SZ; k0 += 32) {
#pragma unroll
    for (int i = 0; i < 2; ++i) {
      int seg = tid + 256 * i;          // 512 segments of 8 bf16 per matrix
      int r = seg >> 2, k8 = (seg & 3) * 8;
      *(s8v*)&As[r][k8] = *(const s8v*)(Ab + (size_t)(m0 + r) * H_SZ + k0 + k8);
      *(s8v*)&Bs[r][k8] = *(const s8v*)(Bb + (size_t)(n0 + r) * H_SZ + k0 + k8);
    }
    __syncthreads();

    s8v af[4], bf[4];
#pragma unroll
    for (int i = 0; i < 4; ++i) af[i] = *(const s8v*)&As[wm + i * 16 + l16][quad * 8];
#pragma unroll
    for (int j = 0; j < 4; ++j) bf[j] = *(const s8v*)&Bs[wn + j * 16 + l16][quad * 8];
#pragma unroll
    for (int i = 0; i < 4; ++i)
#pragma unroll
      for (int j = 0; j < 4; ++j)
        acc[i][j] = __builtin_amdgcn_mfma_f32_16x16x32_bf16(af[i], bf[j], acc[i][j], 0, 0, 0);
    __syncthreads();
  }

  const float C2 = 2.885390082f;  // 2 * log2(e)
  float* Cb = C + strideC * (size_t)b;
#pragma unroll
  for (int i = 0; i < 4; ++i) {
    int m = m0 + wm + i * 16 + quad * 4;  // C/D: row = quad*4 + reg, col = lane&15
#pragma unroll
    for (int j = 0; j < 4; ++j) {
      int n = n0 + wn + j * 16 + l16;
#pragma unroll
      for (int r = 0; r < 4; ++r)
        Cb[(size_t)(m + r) * ldc + n] = exp2f(acc[i][j][r] * C2);
    }
  }
}

// ---------------------------------------------------------------------------
// Score: part[kc][b][d][e] = sum_{k in chunk} vk - 2*vk/(1 + pe[k][e]*pd[d][k])
// (tanh(x) = 1 - 2/(1+e^{2x}), e^{2x} factored into pe*pd by the epilogues)
// ---------------------------------------------------------------------------
#define D_CHUNK 8
#define K_CHUNK 96
#define NKC     8

__global__ __launch_bounds__(256) void score_kernel(const float* __restrict__ peT,
                                                    const float* __restrict__ pdm,
                                                    const float* __restrict__ vt,
                                                    float* __restrict__ part) {
  const int e  = blockIdx.x * 256 + threadIdx.x;
  const int d0 = blockIdx.y * D_CHUNK;
  const int bz = blockIdx.z;
  const int b  = bz >> 3;
  const int kc = bz & 7;
  const int k0 = kc * K_CHUNK;
  const int tid = threadIdx.x;

  __shared__ float pd_s[K_CHUNK][D_CHUNK];
  __shared__ float vts[K_CHUNK];

#pragma unroll
  for (int i = 0; i < 3; ++i) {
    int idx = tid + 256 * i;              // 768 = 8d x 96k
    int d = idx / K_CHUNK, k = idx % K_CHUNK;
    pd_s[k][d] = pdm[((size_t)b * DEC_SZ + d0 + d) * H_SZ + k0 + k];
  }
  if (tid < K_CHUNK) vts[tid] = vt[k0 + tid];
  __syncthreads();

  float sumv = 0.f;
  for (int k = 0; k < K_CHUNK; ++k) sumv += vts[k];

  float t[D_CHUNK];
#pragma unroll
  for (int d = 0; d < D_CHUNK; ++d) t[d] = 0.f;

  const float* ep = peT + ((size_t)b * H_SZ + k0) * ENC_SZ + e;

#pragma unroll 4
  for (int k = 0; k < K_CHUNK; ++k) {
    float pe = ep[(size_t)k * ENC_SZ];
    float vk = vts[k];
    const float4 p0 = *(const float4*)&pd_s[k][0];
    const float4 p1 = *(const float4*)&pd_s[k][4];
    float pd[8] = {p0.x, p0.y, p0.z, p0.w, p1.x, p1.y, p1.z, p1.w};
#pragma unroll
    for (int d = 0; d < D_CHUNK; ++d) {
      float r = __builtin_amdgcn_rcpf(fmaf(pe, pd[d], 1.f));
      t[d] = fmaf(vk, r, t[d]);
    }
  }

  float* pp = part + (size_t)kc * (B_SZ * DEC_SZ * ENC_SZ) +
              ((size_t)b * DEC_SZ + d0) * ENC_SZ + e;
#pragma unroll
  for (int d = 0; d < D_CHUNK; ++d)
    pp[(size_t)d * ENC_SZ] = fmaf(-2.f, t[d], sumv);
}

// ---------------------------------------------------------------------------
// Finalize: sum 8 k-partials, add mask, write both outputs
// ---------------------------------------------------------------------------
__global__ __launch_bounds__(256) void finalize_kernel(const float* __restrict__ part,
                                                       const float* __restrict__ mask,
                                                       float* __restrict__ out) {
  const int N  = B_SZ * DEC_SZ * ENC_SZ;   // 262144
  const int N4 = N / 4;                    // 65536
  int i = blockIdx.x * 256 + threadIdx.x;
  if (i >= N4) return;
  const float4* p = (const float4*)part;
  float4 s = p[i];
#pragma unroll
  for (int kc = 1; kc < NKC; ++kc) {
    float4 q = p[i + kc * N4];
    s.x += q.x; s.y += q.y; s.z += q.z; s.w += q.w;
  }
  float4 m = ((const float4*)mask)[i];
  float4 sm;
  sm.x = s.x + m.x; sm.y = s.y + m.y; sm.z = s.z + m.z; sm.w = s.w + m.w;
  ((float4*)out)[i] = sm;
  ((float4*)(out + N))[i] = s;
}

extern "C" void kernel_launch(void* const* d_in, const int* in_sizes, int n_in,
                              void* d_out, int out_size, void* d_ws, size_t ws_size,
                              hipStream_t stream) {
  (void)in_sizes; (void)n_in; (void)out_size; (void)ws_size;
  const float* dec  = (const float*)d_in[0];  // (B, DEC, H)
  const float* enc  = (const float*)d_in[1];  // (B, ENC, H)
  const float* mask = (const float*)d_in[2];  // (B, DEC, ENC)
  const float* W1   = (const float*)d_in[3];  // (H, H) (k, n)
  const float* W2   = (const float*)d_in[4];  // (H, H) (k, n)
  const float* vt   = (const float*)d_in[5];  // (H,)
  float* out = (float*)d_out;

  // Workspace layout (floats)
  float* peT  = (float*)d_ws;                               // B*H*ENC   (1572864)
  float* pdm  = peT + (size_t)B_SZ * H_SZ * ENC_SZ;         // B*DEC*H   (393216)
  float* part = pdm + (size_t)B_SZ * DEC_SZ * H_SZ;         // 8*B*DEC*ENC (2097152)
  unsigned short* W1T  = (unsigned short*)(part + (size_t)NKC * B_SZ * DEC_SZ * ENC_SZ);
  unsigned short* W2T  = W1T + (size_t)H_SZ * H_SZ;
  unsigned short* encB = W2T + (size_t)H_SZ * H_SZ;         // B*ENC*H bf16
  unsigned short* decB = encB + (size_t)B_SZ * ENC_SZ * H_SZ;

  // Prep: W transposes (bf16) + input casts (bf16)
  transpose_w<<<dim3(12, 12, 2), 256, 0, stream>>>(W1, W2, W1T, W2T);
  cast_bf16<<<dim3((B_SZ * ENC_SZ * H_SZ / 4 + 255) / 256), 256, 0, stream>>>(
      enc, encB, B_SZ * ENC_SZ * H_SZ / 4);
  cast_bf16<<<dim3((B_SZ * DEC_SZ * H_SZ / 4 + 255) / 256), 256, 0, stream>>>(
      dec, decB, B_SZ * DEC_SZ * H_SZ / 4);

  // peT[b][h][e] = exp2(C2 * sum_k W1T[h][k] * enc[b][e][k])
  gemm_nt_exp<<<dim3(H_SZ / 128, ENC_SZ / 128, B_SZ), 256, 0, stream>>>(
      W1T, 0, encB, (size_t)ENC_SZ * H_SZ, peT, (size_t)H_SZ * ENC_SZ, ENC_SZ);
  // pdm[b][d][h] = exp2(C2 * sum_k dec[b][d][k] * W2T[h][k])
  gemm_nt_exp<<<dim3(DEC_SZ / 128, H_SZ / 128, B_SZ), 256, 0, stream>>>(
      decB, (size_t)DEC_SZ * H_SZ, W2T, 0, pdm, (size_t)DEC_SZ * H_SZ, H_SZ);

  // score partials over 8 k-chunks
  score_kernel<<<dim3(ENC_SZ / 256, DEC_SZ / D_CHUNK, B_SZ * NKC), 256, 0, stream>>>(
      peT, pdm, vt, part);
  // reduce + mask + write both outputs
  finalize_kernel<<<dim3(B_SZ * DEC_SZ * ENC_SZ / 4 / 256), 256, 0, stream>>>(
      part, mask, out);
}